// Round 6
// baseline (232.891 us; speedup 1.0000x reference)
//
#include <hip/hip_runtime.h>
#include <stdint.h>

#define S 2048
#define D 256
#define H 8
#define HD 32
#define E_EDGES 65536
#define DFF 1024
#define M_TOK 8192   // B*S
#define CAP 512
#define QKVN 768     // fused q|k|v row stride

typedef __attribute__((ext_vector_type(8))) short s16x8;
typedef __attribute__((ext_vector_type(8))) unsigned short u16x8;
typedef __attribute__((ext_vector_type(4))) unsigned short u16x4v;
typedef __attribute__((ext_vector_type(4))) float f32x4;

__device__ __forceinline__ float b2f(unsigned short u){
  union { unsigned int i; float f; } x; x.i = ((unsigned int)u) << 16; return x.f;
}
__device__ __forceinline__ unsigned short f2b(float f){
  union { float f; unsigned int i; } x; x.f = f;
  unsigned int r = x.i + 0x7fffu + ((x.i >> 16) & 1u);
  return (unsigned short)(r >> 16);
}
__device__ __forceinline__ void gload_lds16(const void* g, void* l) {
  __builtin_amdgcn_global_load_lds(
      (const __attribute__((address_space(1))) unsigned int*)g,
      (__attribute__((address_space(3))) unsigned int*)l, 16, 0, 0);
}

// ---------------- f32 -> bf16 conversion (weights) ------------------------------
__global__ __launch_bounds__(256) void cvt_kernel(
    const float* __restrict__ in, unsigned short* __restrict__ out, int n4)
{
  int i = blockIdx.x * 256 + threadIdx.x;
  if (i >= n4) return;
  const float4 v = *(const float4*)(in + (size_t)i * 4);
  unsigned short o[4] = { f2b(v.x), f2b(v.y), f2b(v.z), f2b(v.w) };
  *(uint2*)(out + (size_t)i * 4) = *(const uint2*)o;
}

// ---------------- LayerNorm (f32 input -> bf16 out), 1 wave per row ------------
__global__ __launch_bounds__(256) void ln_kernel(
    const float* __restrict__ xf,
    const float* __restrict__ g, const float* __restrict__ bt,
    unsigned short* __restrict__ out)
{
  const int wave = threadIdx.x >> 6;
  const int lane = threadIdx.x & 63;
  const int row = blockIdx.x * 4 + wave;
  const size_t base = (size_t)row * D + lane * 4;
  const float4 u = *(const float4*)(xf + base);
  float v[4] = { u.x, u.y, u.z, u.w };
  float s  = v[0]+v[1]+v[2]+v[3];
  float s2 = v[0]*v[0]+v[1]*v[1]+v[2]*v[2]+v[3]*v[3];
  #pragma unroll
  for (int off=32; off>=1; off>>=1){ s += __shfl_xor(s,off,64); s2 += __shfl_xor(s2,off,64); }
  const float mu  = s * (1.f/D);
  const float var = s2 * (1.f/D) - mu*mu;
  const float rs  = 1.f / sqrtf(var + 1e-5f);
  #pragma unroll
  for (int j=0;j<4;++j){
    const int c = lane*4 + j;
    const float y = (v[j]-mu)*rs*g[c] + bt[c];
    out[(size_t)row*D + c] = f2b(y);
  }
}

// ---------------- GEMM (m97-style): C = epi(A[MxK] * W[NxK]^T + bias) -----------
// linear LDS [rows][32] bf16, global_load_lds width-16 staging, BK=32.
template<int BM, int BN, int WR, int WC>
__global__ __launch_bounds__(256) void gemm_lds(
    const unsigned short* __restrict__ A,
    const unsigned short* __restrict__ W,
    const float* __restrict__ bias,
    unsigned short* __restrict__ outb,
    float* __restrict__ outf,
    const float* __restrict__ resf,
    int M, int N, int K, int act)
{
  constexpr int WM = BM / WR, WN = BN / WC;
  constexpr int MI = WM / 16, NI = WN / 16;
  __shared__ unsigned short As[BM * 32];
  __shared__ unsigned short Bs[BN * 32];
  const int tid  = threadIdx.x;
  const int wave = tid >> 6;
  const int lane = tid & 63;
  const int wr = wave / WC, wc = wave % WC;
  const int m0 = blockIdx.y * BM;
  const int n0 = blockIdx.x * BN;
  // staging map: 1KB chunk = 16 rows; lane -> row lane>>2, col (lane&3)*8
  const int ldr = lane >> 2;
  const int ldc = (lane & 3) * 8;
  const int fr = lane & 15;
  const int kf = (lane >> 4) * 8;
  f32x4 acc[MI][NI];
  #pragma unroll
  for (int i=0;i<MI;++i)
    #pragma unroll
    for (int j=0;j<NI;++j)
      #pragma unroll
      for (int r=0;r<4;++r) acc[i][j][r] = 0.f;

  for (int k0 = 0; k0 < K; k0 += 32) {
    #pragma unroll
    for (int c = wave; c < BM/16; c += 4)
      gload_lds16(A + (size_t)(m0 + c*16 + ldr)*K + k0 + ldc, &As[c*512]);
    #pragma unroll
    for (int c = wave; c < BN/16; c += 4)
      gload_lds16(W + (size_t)(n0 + c*16 + ldr)*K + k0 + ldc, &Bs[c*512]);
    __syncthreads();
    s16x8 af[MI], bf[NI];
    #pragma unroll
    for (int i = 0; i < MI; ++i) af[i] = *(const s16x8*)&As[(wr*WM + i*16 + fr)*32 + kf];
    #pragma unroll
    for (int j = 0; j < NI; ++j) bf[j] = *(const s16x8*)&Bs[(wc*WN + j*16 + fr)*32 + kf];
    #pragma unroll
    for (int i = 0; i < MI; ++i)
      #pragma unroll
      for (int j = 0; j < NI; ++j)
        acc[i][j] = __builtin_amdgcn_mfma_f32_16x16x32_bf16(af[i], bf[j], acc[i][j], 0, 0, 0);
    __syncthreads();
  }
  const int rbase = (lane >> 4) * 4;
  #pragma unroll
  for (int j = 0; j < NI; ++j) {
    const int col = n0 + wc*WN + j*16 + fr;
    const float bvl = bias[col];
    #pragma unroll
    for (int i = 0; i < MI; ++i) {
      #pragma unroll
      for (int r = 0; r < 4; ++r) {
        const int row = m0 + wr*WM + i*16 + rbase + r;
        const size_t off = (size_t)row * N + col;
        float vv = acc[i][j][r] + bvl;
        if (act) vv = 0.5f * vv * (1.0f + erff(vv * 0.70710678118654752f));
        if (resf) vv += resf[off];
        if (outb) outb[off] = f2b(vv);
        if (outf) outf[off] = vv;
      }
    }
  }
}

// ---------------- edge-bias scatter (np last-write-wins via packed atomicMax) ----
__global__ __launch_bounds__(256) void zero_kernel(uint4* __restrict__ p, int n4) {
  int i = blockIdx.x * 256 + threadIdx.x;
  if (i < n4) { uint4 z; z.x=0; z.y=0; z.z=0; z.w=0; p[i] = z; }
}
__global__ __launch_bounds__(256) void scatter_kernel(
    const int* __restrict__ ei, const float* __restrict__ attr,
    unsigned int* __restrict__ packed)
{
  int e = blockIdx.x * 256 + threadIdx.x;
  if (e >= E_EDGES) return;
  int r = ei[e], c = ei[E_EDGES + e];
  float v = attr[e];
  v = fminf(5.f, fmaxf(-5.f, v));
  unsigned int pk = (((unsigned int)e) << 16) | (unsigned int)f2b(v);
  atomicMax(&packed[(size_t)r * S + c], pk);
}

// ---------------- sparse masked attention: 1 block per (b, q-row) ---------------
// wave-per-neighbor: one 512B coalesced row load covers all 8 heads.
__global__ __launch_bounds__(256) void attn_kernel(
    const unsigned short* __restrict__ qkv,
    const int* __restrict__ mask,
    const unsigned int* __restrict__ packed,
    unsigned short* __restrict__ ctx)
{
  __shared__ unsigned short nidx[CAP];
  __shared__ float nbias[CAP];
  __shared__ float sc[CAP*9];       // [n][h] stride 9
  __shared__ float qs[D];
  __shared__ float red[4*D];
  __shared__ int wtot[4], wbase[4], cnt_s;
  const int t = threadIdx.x;
  const int wave = t >> 6, lane = t & 63;
  const int bqi = blockIdx.x;          // b*S + qrow
  const int b = bqi >> 11;
  const int qrow = bqi & (S-1);
  qs[t] = b2f(qkv[(size_t)bqi * QKVN + t]);

  // deterministic mask-row compaction (mask = int32 0/1, 8 columns per thread)
  const int* mrow = mask + (size_t)bqi * S;
  const uint4 ma = *(const uint4*)(mrow + t*8);
  const uint4 mb = *(const uint4*)(mrow + t*8 + 4);
  unsigned int mv[8] = { ma.x, ma.y, ma.z, ma.w, mb.x, mb.y, mb.z, mb.w };
  int mycnt = 0;
  #pragma unroll
  for (int j = 0; j < 8; ++j) mycnt += mv[j] ? 1 : 0;
  int inc = mycnt;
  #pragma unroll
  for (int off=1; off<64; off<<=1){ int y = __shfl_up(inc, off, 64); if (lane >= off) inc += y; }
  if (lane == 63) wtot[wave] = inc;
  __syncthreads();
  if (t == 0) { int ss=0; for (int w=0; w<4; ++w){ wbase[w]=ss; ss+=wtot[w]; } cnt_s = ss; }
  __syncthreads();
  int pos = wbase[wave] + inc - mycnt;
  #pragma unroll
  for (int j = 0; j < 8; ++j) {
    if (mv[j]) {
      if (pos < CAP) nidx[pos] = (unsigned short)(t*8 + j);
      ++pos;
    }
  }
  __syncthreads();
  int cnt = cnt_s; if (cnt > CAP) cnt = CAP;

  for (int i = t; i < cnt; i += 256) {
    unsigned int pkv = packed[(size_t)qrow * S + nidx[i]];
    nbias[i] = b2f((unsigned short)(pkv & 0xffffu));   // empty slot -> bits 0 -> +0.0
  }
  __syncthreads();

  // wave-per-neighbor layout: lane covers head hh = lane>>3, dims d4..d4+3
  const int hh = lane >> 3;
  const int d4 = (lane & 7) * 4;
  const float scale = 0.17677669529663687f;  // 1/sqrt(32)
  float q4[4];
  #pragma unroll
  for (int j = 0; j < 4; ++j) q4[j] = qs[hh*HD + d4 + j];
  const size_t rowbase = (size_t)b * S * QKVN;

  // scores: per neighbor, one 512B wave load of the K row
  for (int n = wave; n < cnt; n += 4) {
    const unsigned short* krow = qkv + rowbase + (size_t)nidx[n] * QKVN + 256;
    u16x4v kv = *(const u16x4v*)(krow + lane*4);
    float p = q4[0]*b2f(kv[0]) + q4[1]*b2f(kv[1]) + q4[2]*b2f(kv[2]) + q4[3]*b2f(kv[3]);
    p += __shfl_xor(p, 1, 64);
    p += __shfl_xor(p, 2, 64);
    p += __shfl_xor(p, 4, 64);
    if ((lane & 7) == 0) sc[n*9 + hh] = p * scale + nbias[n];
  }
  __syncthreads();

  // per-head softmax (32 lanes per head), normalize in place
  if (cnt > 0) {
    const int h = t >> 5, dd = t & 31;
    float m = -1e30f;
    for (int n = dd; n < cnt; n += 32) m = fmaxf(m, sc[n*9 + h]);
    #pragma unroll
    for (int off=16; off>=1; off>>=1) m = fmaxf(m, __shfl_xor(m, off, 64));
    float sum = 0.f;
    for (int n = dd; n < cnt; n += 32) {
      float e = __expf(sc[n*9 + h] - m);
      sc[n*9 + h] = e;
      sum += e;
    }
    #pragma unroll
    for (int off=16; off>=1; off>>=1) sum += __shfl_xor(sum, off, 64);
    const float rinv = 1.f / sum;
    for (int n = dd; n < cnt; n += 32) sc[n*9 + h] *= rinv;
  }
  __syncthreads();

  // PV: per neighbor, one 512B wave load of the V row; per-wave partial acc
  float a4[4] = {0.f, 0.f, 0.f, 0.f};
  if (cnt > 0) {
    for (int n = wave; n < cnt; n += 4) {
      const unsigned short* vrow = qkv + rowbase + (size_t)nidx[n] * QKVN + 512;
      u16x4v vv = *(const u16x4v*)(vrow + lane*4);
      const float p = sc[n*9 + hh];
      a4[0] += p * b2f(vv[0]);
      a4[1] += p * b2f(vv[1]);
      a4[2] += p * b2f(vv[2]);
      a4[3] += p * b2f(vv[3]);
    }
  } else {
    // fully-masked row: reference softmax degenerates to uniform 1/S
    for (int n = wave; n < S; n += 4) {
      const unsigned short* vrow = qkv + rowbase + (size_t)n * QKVN + 512;
      u16x4v vv = *(const u16x4v*)(vrow + lane*4);
      a4[0] += b2f(vv[0]); a4[1] += b2f(vv[1]); a4[2] += b2f(vv[2]); a4[3] += b2f(vv[3]);
    }
    #pragma unroll
    for (int j = 0; j < 4; ++j) a4[j] *= (1.f / S);
  }
  // cross-wave reduce (dim index = lane*4+j = hh*32+d4+j)
  #pragma unroll
  for (int j = 0; j < 4; ++j) red[wave*D + lane*4 + j] = a4[j];
  __syncthreads();
  float outv = red[t] + red[D + t] + red[2*D + t] + red[3*D + t];
  ctx[(size_t)bqi * D + t] = f2b(outv);
}

extern "C" void kernel_launch(void* const* d_in, const int* in_sizes, int n_in,
                              void* d_out, int out_size, void* d_ws, size_t ws_size,
                              hipStream_t stream) {
  const float*          x    = (const float*)d_in[0];
  const int*            mask = (const int*)d_in[1];
  const float*          eat  = (const float*)d_in[2];
  const int*            eidx = (const int*)d_in[3];
  const float*          ln1g = (const float*)d_in[4];
  const float*          ln1b = (const float*)d_in[5];
  const float*          wq   = (const float*)d_in[6];
  const float*          bq   = (const float*)d_in[7];
  const float*          wk   = (const float*)d_in[8];
  const float*          bk   = (const float*)d_in[9];
  const float*          wv   = (const float*)d_in[10];
  const float*          bv   = (const float*)d_in[11];
  const float*          wo   = (const float*)d_in[12];
  const float*          bo   = (const float*)d_in[13];
  const float*          ln2g = (const float*)d_in[14];
  const float*          ln2b = (const float*)d_in[15];
  const float*          w1   = (const float*)d_in[16];
  const float*          b1   = (const float*)d_in[17];
  const float*          w2   = (const float*)d_in[18];
  const float*          b2   = (const float*)d_in[19];
  float* out = (float*)d_out;

  // workspace layout (element offsets)
  char* ws = (char*)d_ws;
  unsigned short* nx   = (unsigned short*)ws;                     // 4MB, reused as n2
  unsigned short* qkv  = nx + (size_t)M_TOK*D;                    // 12MB
  unsigned short* cx   = qkv + (size_t)M_TOK*QKVN;                // 4MB
  float*          x1   = (float*)(cx + (size_t)M_TOK*D);          // 8MB
  unsigned int*   pk   = (unsigned int*)(x1 + (size_t)M_TOK*D);   // 16MB
  unsigned short* wqkvb= (unsigned short*)(pk + (size_t)S*S);     // 384KB
  unsigned short* wob  = wqkvb + (size_t)QKVN*D;                  // 128KB
  unsigned short* w1b  = wob + (size_t)D*D;                       // 512KB
  unsigned short* w2b  = w1b + (size_t)DFF*D;                     // 512KB
  float*          bqkv = (float*)(w2b + (size_t)D*DFF);           // 3KB
  unsigned short* hb   = qkv;  // overlay: qkv+cx (16MB) dead by MLP1
  unsigned short* n2   = nx;   // overlay: nx dead by LN2

  // weight conversion + concatenation
  cvt_kernel<<<D*D/4/256,   256, 0, stream>>>(wq, wqkvb,               D*D/4);
  cvt_kernel<<<D*D/4/256,   256, 0, stream>>>(wk, wqkvb + (size_t)D*D,   D*D/4);
  cvt_kernel<<<D*D/4/256,   256, 0, stream>>>(wv, wqkvb + (size_t)2*D*D, D*D/4);
  cvt_kernel<<<D*D/4/256,   256, 0, stream>>>(wo, wob, D*D/4);
  cvt_kernel<<<DFF*D/4/256, 256, 0, stream>>>(w1, w1b, DFF*D/4);
  cvt_kernel<<<DFF*D/4/256, 256, 0, stream>>>(w2, w2b, DFF*D/4);
  hipMemcpyAsync(bqkv,       bq, D*sizeof(float), hipMemcpyDeviceToDevice, stream);
  hipMemcpyAsync(bqkv + D,   bk, D*sizeof(float), hipMemcpyDeviceToDevice, stream);
  hipMemcpyAsync(bqkv + 2*D, bv, D*sizeof(float), hipMemcpyDeviceToDevice, stream);

  zero_kernel<<<(S*S/4 + 255)/256, 256, 0, stream>>>((uint4*)pk, S*S/4);
  scatter_kernel<<<E_EDGES/256, 256, 0, stream>>>(eidx, eat, pk);
  ln_kernel<<<M_TOK/4, 256, 0, stream>>>(x, ln1g, ln1b, nx);
  gemm_lds<64,128,1,4><<<dim3(QKVN/128, M_TOK/64), 256, 0, stream>>>(nx, wqkvb, bqkv, qkv, nullptr, nullptr, M_TOK, QKVN, D, 0);
  attn_kernel<<<M_TOK, 256, 0, stream>>>(qkv, mask, pk, cx);
  gemm_lds<64,64,2,2><<<dim3(D/64, M_TOK/64), 256, 0, stream>>>(cx, wob, bo, nullptr, x1, x, M_TOK, D, D, 0);
  ln_kernel<<<M_TOK/4, 256, 0, stream>>>(x1, ln2g, ln2b, n2);
  gemm_lds<128,128,2,2><<<dim3(DFF/128, M_TOK/128), 256, 0, stream>>>(n2, w1b, b1, hb, nullptr, nullptr, M_TOK, DFF, D, 1);
  gemm_lds<64,64,2,2><<<dim3(D/64, M_TOK/64), 256, 0, stream>>>(hb, w2b, b2, nullptr, out, x1, M_TOK, D, DFF, 0);
}

// Round 7
// 177.598 us; speedup vs baseline: 1.3113x; 1.3113x over previous
//
#include <hip/hip_runtime.h>
#include <stdint.h>

#define S 2048
#define D 256
#define H 8
#define HD 32
#define E_EDGES 65536
#define DFF 1024
#define M_TOK 8192   // B*S
#define CAP 512
#define QKVN 768     // fused q|k|v row stride

typedef __attribute__((ext_vector_type(8))) short s16x8;
typedef __attribute__((ext_vector_type(8))) unsigned short u16x8;
typedef __attribute__((ext_vector_type(4))) unsigned short u16x4v;
typedef __attribute__((ext_vector_type(4))) float f32x4;

__device__ __forceinline__ float b2f(unsigned short u){
  union { unsigned int i; float f; } x; x.i = ((unsigned int)u) << 16; return x.f;
}
__device__ __forceinline__ unsigned short f2b(float f){
  union { float f; unsigned int i; } x; x.f = f;
  unsigned int r = x.i + 0x7fffu + ((x.i >> 16) & 1u);
  return (unsigned short)(r >> 16);
}
__device__ __forceinline__ void gload_lds16(const void* g, void* l) {
  __builtin_amdgcn_global_load_lds(
      (const __attribute__((address_space(1))) unsigned int*)g,
      (__attribute__((address_space(3))) unsigned int*)l, 16, 0, 0);
}

// ------------- one-shot weight prep: f32->bf16 for all weights + bias concat ----
__global__ __launch_bounds__(256) void prep_kernel(
    const float* __restrict__ wq, const float* __restrict__ wk,
    const float* __restrict__ wv, const float* __restrict__ wo,
    const float* __restrict__ w1, const float* __restrict__ w2,
    const float* __restrict__ bq, const float* __restrict__ bk,
    const float* __restrict__ bv,
    unsigned short* __restrict__ wqkvb, unsigned short* __restrict__ wob,
    unsigned short* __restrict__ w1b, unsigned short* __restrict__ w2b,
    float* __restrict__ bqkv)
{
  const int i = blockIdx.x * 256 + threadIdx.x;   // float4 index, 196608 total
  const float* src; unsigned short* dst; int off;
  if      (i <  16384) { src = wq; dst = wqkvb;            off = i; }
  else if (i <  32768) { src = wk; dst = wqkvb +  65536;   off = i -  16384; }
  else if (i <  49152) { src = wv; dst = wqkvb + 131072;   off = i -  32768; }
  else if (i <  65536) { src = wo; dst = wob;              off = i -  49152; }
  else if (i < 131072) { src = w1; dst = w1b;              off = i -  65536; }
  else                 { src = w2; dst = w2b;              off = i - 131072; }
  const float4 v = ((const float4*)src)[off];
  unsigned short o[4] = { f2b(v.x), f2b(v.y), f2b(v.z), f2b(v.w) };
  *(uint2*)(dst + (size_t)off * 4) = *(const uint2*)o;
  if      (i <  64) ((float4*)bqkv)[i]       = ((const float4*)bq)[i];
  else if (i < 128) ((float4*)bqkv)[i - 64]  = ((const float4*)bk)[i - 64],  ((float4*)bqkv)[i] = ((const float4*)bk)[i - 64];
}

// fix bias concat cleanly (separate tiny ranges; above line kept simple):
__global__ __launch_bounds__(192) void bias_kernel(
    const float* __restrict__ bq, const float* __restrict__ bk,
    const float* __restrict__ bv, float* __restrict__ bqkv)
{
  const int i = threadIdx.x;   // 0..191 float4
  if      (i <  64) ((float4*)bqkv)[i] = ((const float4*)bq)[i];
  else if (i < 128) ((float4*)bqkv)[i] = ((const float4*)bk)[i - 64];
  else              ((float4*)bqkv)[i] = ((const float4*)bv)[i - 128];
}

// ---------------- LayerNorm (f32 input -> bf16 out), 1 wave per row ------------
__global__ __launch_bounds__(256) void ln_kernel(
    const float* __restrict__ xf,
    const float* __restrict__ g, const float* __restrict__ bt,
    unsigned short* __restrict__ out)
{
  const int wave = threadIdx.x >> 6;
  const int lane = threadIdx.x & 63;
  const int row = blockIdx.x * 4 + wave;
  const size_t base = (size_t)row * D + lane * 4;
  const float4 u = *(const float4*)(xf + base);
  float v[4] = { u.x, u.y, u.z, u.w };
  float s  = v[0]+v[1]+v[2]+v[3];
  float s2 = v[0]*v[0]+v[1]*v[1]+v[2]*v[2]+v[3]*v[3];
  #pragma unroll
  for (int off=32; off>=1; off>>=1){ s += __shfl_xor(s,off,64); s2 += __shfl_xor(s2,off,64); }
  const float mu  = s * (1.f/D);
  const float var = s2 * (1.f/D) - mu*mu;
  const float rs  = 1.f / sqrtf(var + 1e-5f);
  #pragma unroll
  for (int j=0;j<4;++j){
    const int c = lane*4 + j;
    const float y = (v[j]-mu)*rs*g[c] + bt[c];
    out[(size_t)row*D + c] = f2b(y);
  }
}

// ---------------- GEMM, 2-phase double-buffered (T3 minimum recipe) -------------
// linear LDS [rows][32] bf16 per buffer, global_load_lds width-16 staging, BK=32.
template<int BM, int BN, int WR, int WC>
__global__ __launch_bounds__(256) void gemm_lds(
    const unsigned short* __restrict__ A,
    const unsigned short* __restrict__ W,
    const float* __restrict__ bias,
    unsigned short* __restrict__ outb,
    float* __restrict__ outf,
    const float* __restrict__ resf,
    int M, int N, int K, int act)
{
  constexpr int WM = BM / WR, WN = BN / WC;
  constexpr int MI = WM / 16, NI = WN / 16;
  __shared__ unsigned short As[2][BM * 32];
  __shared__ unsigned short Bs[2][BN * 32];
  const int tid  = threadIdx.x;
  const int wave = tid >> 6;
  const int lane = tid & 63;
  const int wr = wave / WC, wc = wave % WC;
  const int m0 = blockIdx.y * BM;
  const int n0 = blockIdx.x * BN;
  const int ldr = lane >> 2;
  const int ldc = (lane & 3) * 8;
  const int fr = lane & 15;
  const int kf = (lane >> 4) * 8;
  f32x4 acc[MI][NI];
  #pragma unroll
  for (int i=0;i<MI;++i)
    #pragma unroll
    for (int j=0;j<NI;++j)
      #pragma unroll
      for (int r=0;r<4;++r) acc[i][j][r] = 0.f;

  auto stage = [&](int buf, int k0) {
    #pragma unroll
    for (int c = wave; c < BM/16; c += 4)
      gload_lds16(A + (size_t)(m0 + c*16 + ldr)*K + k0 + ldc, &As[buf][c*512]);
    #pragma unroll
    for (int c = wave; c < BN/16; c += 4)
      gload_lds16(W + (size_t)(n0 + c*16 + ldr)*K + k0 + ldc, &Bs[buf][c*512]);
  };

  stage(0, 0);
  __syncthreads();          // vmcnt(0) drain: buf0 resident
  int cur = 0;
  for (int k0 = 0; k0 < K; k0 += 32) {
    if (k0 + 32 < K) stage(cur ^ 1, k0 + 32);   // prefetch flies during MFMA
    s16x8 af[MI], bf[NI];
    #pragma unroll
    for (int i = 0; i < MI; ++i) af[i] = *(const s16x8*)&As[cur][(wr*WM + i*16 + fr)*32 + kf];
    #pragma unroll
    for (int j = 0; j < NI; ++j) bf[j] = *(const s16x8*)&Bs[cur][(wc*WN + j*16 + fr)*32 + kf];
    #pragma unroll
    for (int i = 0; i < MI; ++i)
      #pragma unroll
      for (int j = 0; j < NI; ++j)
        acc[i][j] = __builtin_amdgcn_mfma_f32_16x16x32_bf16(af[i], bf[j], acc[i][j], 0, 0, 0);
    __syncthreads();        // drains prefetch; protects cur from next overwrite
    cur ^= 1;
  }
  const int rbase = (lane >> 4) * 4;
  #pragma unroll
  for (int j = 0; j < NI; ++j) {
    const int col = n0 + wc*WN + j*16 + fr;
    const float bvl = bias[col];
    #pragma unroll
    for (int i = 0; i < MI; ++i) {
      #pragma unroll
      for (int r = 0; r < 4; ++r) {
        const int row = m0 + wr*WM + i*16 + rbase + r;
        const size_t off = (size_t)row * N + col;
        float vv = acc[i][j][r] + bvl;
        if (act) vv = 0.5f * vv * (1.0f + erff(vv * 0.70710678118654752f));
        if (resf) vv += resf[off];
        if (outb) outb[off] = f2b(vv);
        if (outf) outf[off] = vv;
      }
    }
  }
}

// ---------------- edge-bias scatter (np last-write-wins via packed atomicMax) ----
__global__ __launch_bounds__(256) void zero_kernel(uint4* __restrict__ p, int n4) {
  int i = blockIdx.x * 256 + threadIdx.x;
  if (i < n4) { uint4 z; z.x=0; z.y=0; z.z=0; z.w=0; p[i] = z; }
}
__global__ __launch_bounds__(256) void scatter_kernel(
    const int* __restrict__ ei, const float* __restrict__ attr,
    unsigned int* __restrict__ packed)
{
  int e = blockIdx.x * 256 + threadIdx.x;
  if (e >= E_EDGES) return;
  int r = ei[e], c = ei[E_EDGES + e];
  float v = attr[e];
  v = fminf(5.f, fmaxf(-5.f, v));
  unsigned int pk = (((unsigned int)e) << 16) | (unsigned int)f2b(v);
  atomicMax(&packed[(size_t)r * S + c], pk);
}

// ---------------- sparse masked attention: 1 block per (b, q-row) ---------------
// wave-per-neighbor, 8-deep unrolled gathers (8 outstanding 512B loads per wave).
__global__ __launch_bounds__(256) void attn_kernel(
    const unsigned short* __restrict__ qkv,
    const int* __restrict__ mask,
    const unsigned int* __restrict__ packed,
    unsigned short* __restrict__ ctx)
{
  __shared__ unsigned short nidx[CAP];
  __shared__ float nbias[CAP];
  __shared__ float sc[CAP*9];       // [n][h] stride 9
  __shared__ float qs[D];
  __shared__ float red[4*D];
  __shared__ float rsum[H];
  __shared__ int wtot[4], wbase[4], cnt_s;
  const int t = threadIdx.x;
  const int wave = t >> 6, lane = t & 63;
  const int bqi = blockIdx.x;          // b*S + qrow
  const int b = bqi >> 11;
  const int qrow = bqi & (S-1);
  qs[t] = b2f(qkv[(size_t)bqi * QKVN + t]);

  // deterministic mask-row compaction (mask = int32 0/1, 8 columns per thread)
  const int* mrow = mask + (size_t)bqi * S;
  const uint4 ma = *(const uint4*)(mrow + t*8);
  const uint4 mb = *(const uint4*)(mrow + t*8 + 4);
  unsigned int mv[8] = { ma.x, ma.y, ma.z, ma.w, mb.x, mb.y, mb.z, mb.w };
  int mycnt = 0;
  #pragma unroll
  for (int j = 0; j < 8; ++j) mycnt += mv[j] ? 1 : 0;
  int inc = mycnt;
  #pragma unroll
  for (int off=1; off<64; off<<=1){ int y = __shfl_up(inc, off, 64); if (lane >= off) inc += y; }
  if (lane == 63) wtot[wave] = inc;
  __syncthreads();
  if (t == 0) { int ss=0; for (int w=0; w<4; ++w){ wbase[w]=ss; ss+=wtot[w]; } cnt_s = ss; }
  __syncthreads();
  int pos = wbase[wave] + inc - mycnt;
  #pragma unroll
  for (int j = 0; j < 8; ++j) {
    if (mv[j]) {
      if (pos < CAP) nidx[pos] = (unsigned short)(t*8 + j);
      ++pos;
    }
  }
  __syncthreads();
  int cnt = cnt_s; if (cnt > CAP) cnt = CAP;
  const int cnt_pad = (cnt + 31) & ~31;           // multiple of 4 waves * 8 unroll
  for (int i = cnt + t; i < cnt_pad; i += 256) nidx[i] = 0;

  for (int i = t; i < cnt; i += 256) {
    unsigned int pkv = packed[(size_t)qrow * S + nidx[i]];
    nbias[i] = b2f((unsigned short)(pkv & 0xffffu));   // empty slot -> bits 0 -> +0.0
  }
  __syncthreads();

  // wave-per-neighbor layout: lane covers head hh = lane>>3, dims d4..d4+3
  const int hh = lane >> 3;
  const int d4 = (lane & 7) * 4;
  const float scale = 0.17677669529663687f;  // 1/sqrt(32)
  float q4[4];
  #pragma unroll
  for (int j = 0; j < 4; ++j) q4[j] = qs[hh*HD + d4 + j];
  const size_t rowbase = (size_t)b * S * QKVN;

  // scores: 8 neighbors per wave per sweep -> 8 outstanding 512B loads
  for (int n0 = wave*8; n0 < cnt_pad; n0 += 32) {
    u16x4v kv[8];
    #pragma unroll
    for (int u = 0; u < 8; ++u)
      kv[u] = *(const u16x4v*)(qkv + rowbase + (size_t)nidx[n0+u]*QKVN + 256 + lane*4);
    #pragma unroll
    for (int u = 0; u < 8; ++u) {
      float p = q4[0]*b2f(kv[u][0]) + q4[1]*b2f(kv[u][1]) + q4[2]*b2f(kv[u][2]) + q4[3]*b2f(kv[u][3]);
      p += __shfl_xor(p, 1, 64);
      p += __shfl_xor(p, 2, 64);
      p += __shfl_xor(p, 4, 64);
      if ((lane & 7) == 0) {
        const int n = n0 + u;
        sc[n*9 + hh] = (n < cnt) ? p * scale + nbias[n] : 0.f;
      }
    }
  }
  __syncthreads();

  // per-head softmax (32 lanes per head); keep exp in sc, 1/sum in rsum[h]
  if (cnt > 0) {
    const int h = t >> 5, dd = t & 31;
    float m = -1e30f;
    for (int n = dd; n < cnt; n += 32) m = fmaxf(m, sc[n*9 + h]);
    #pragma unroll
    for (int off=16; off>=1; off>>=1) m = fmaxf(m, __shfl_xor(m, off, 64));
    float sum = 0.f;
    for (int n = dd; n < cnt; n += 32) {
      float e = __expf(sc[n*9 + h] - m);
      sc[n*9 + h] = e;
      sum += e;
    }
    #pragma unroll
    for (int off=16; off>=1; off>>=1) sum += __shfl_xor(sum, off, 64);
    if (dd == 0) rsum[h] = 1.f / sum;
  }
  __syncthreads();

  // PV: 8 neighbors per wave per sweep, per-wave partial acc, fold 1/sum at end
  float a4[4] = {0.f, 0.f, 0.f, 0.f};
  if (cnt > 0) {
    for (int n0 = wave*8; n0 < cnt_pad; n0 += 32) {
      u16x4v vv[8];
      #pragma unroll
      for (int u = 0; u < 8; ++u)
        vv[u] = *(const u16x4v*)(qkv + rowbase + (size_t)nidx[n0+u]*QKVN + 512 + lane*4);
      #pragma unroll
      for (int u = 0; u < 8; ++u) {
        const float p = sc[(n0+u)*9 + hh];     // 0 for padded slots
        a4[0] += p * b2f(vv[u][0]);
        a4[1] += p * b2f(vv[u][1]);
        a4[2] += p * b2f(vv[u][2]);
        a4[3] += p * b2f(vv[u][3]);
      }
    }
    const float rinv = rsum[hh];
    #pragma unroll
    for (int j = 0; j < 4; ++j) a4[j] *= rinv;
  } else {
    // fully-masked row: reference softmax degenerates to uniform 1/S
    for (int n = wave; n < S; n += 4) {
      const unsigned short* vrow = qkv + rowbase + (size_t)n * QKVN + 512;
      u16x4v vv = *(const u16x4v*)(vrow + lane*4);
      a4[0] += b2f(vv[0]); a4[1] += b2f(vv[1]); a4[2] += b2f(vv[2]); a4[3] += b2f(vv[3]);
    }
    #pragma unroll
    for (int j = 0; j < 4; ++j) a4[j] *= (1.f / S);
  }
  // cross-wave reduce (dim index = lane*4+j = hh*32+d4+j)
  #pragma unroll
  for (int j = 0; j < 4; ++j) red[wave*D + lane*4 + j] = a4[j];
  __syncthreads();
  float outv = red[t] + red[D + t] + red[2*D + t] + red[3*D + t];
  ctx[(size_t)bqi * D + t] = f2b(outv);
}

extern "C" void kernel_launch(void* const* d_in, const int* in_sizes, int n_in,
                              void* d_out, int out_size, void* d_ws, size_t ws_size,
                              hipStream_t stream) {
  const float*          x    = (const float*)d_in[0];
  const int*            mask = (const int*)d_in[1];
  const float*          eat  = (const float*)d_in[2];
  const int*            eidx = (const int*)d_in[3];
  const float*          ln1g = (const float*)d_in[4];
  const float*          ln1b = (const float*)d_in[5];
  const float*          wq   = (const float*)d_in[6];
  const float*          bq   = (const float*)d_in[7];
  const float*          wk   = (const float*)d_in[8];
  const float*          bk   = (const float*)d_in[9];
  const float*          wv   = (const float*)d_in[10];
  const float*          bv   = (const float*)d_in[11];
  const float*          wo   = (const float*)d_in[12];
  const float*          bo   = (const float*)d_in[13];
  const float*          ln2g = (const float*)d_in[14];
  const float*          ln2b = (const float*)d_in[15];
  const float*          w1   = (const float*)d_in[16];
  const float*          b1   = (const float*)d_in[17];
  const float*          w2   = (const float*)d_in[18];
  const float*          b2   = (const float*)d_in[19];
  float* out = (float*)d_out;

  // workspace layout (element offsets)
  char* ws = (char*)d_ws;
  unsigned short* nx   = (unsigned short*)ws;                     // 4MB, reused as n2
  unsigned short* qkv  = nx + (size_t)M_TOK*D;                    // 12MB
  unsigned short* cx   = qkv + (size_t)M_TOK*QKVN;                // 4MB
  float*          x1   = (float*)(cx + (size_t)M_TOK*D);          // 8MB
  unsigned int*   pk   = (unsigned int*)(x1 + (size_t)M_TOK*D);   // 16MB
  unsigned short* wqkvb= (unsigned short*)(pk + (size_t)S*S);     // 384KB
  unsigned short* wob  = wqkvb + (size_t)QKVN*D;                  // 128KB
  unsigned short* w1b  = wob + (size_t)D*D;                       // 512KB
  unsigned short* w2b  = w1b + (size_t)DFF*D;                     // 512KB
  float*          bqkv = (float*)(w2b + (size_t)D*DFF);           // 3KB
  unsigned short* hb   = qkv;  // overlay: qkv+cx (16MB) dead by MLP1
  unsigned short* n2   = nx;   // overlay: nx dead by LN2

  prep_kernel<<<768, 256, 0, stream>>>(wq, wk, wv, wo, w1, w2, bq, bk, bv,
                                       wqkvb, wob, w1b, w2b, bqkv);
  bias_kernel<<<1, 192, 0, stream>>>(bq, bk, bv, bqkv);
  zero_kernel<<<(S*S/4 + 255)/256, 256, 0, stream>>>((uint4*)pk, S*S/4);
  scatter_kernel<<<E_EDGES/256, 256, 0, stream>>>(eidx, eat, pk);
  ln_kernel<<<M_TOK/4, 256, 0, stream>>>(x, ln1g, ln1b, nx);
  gemm_lds<64,128,1,4><<<dim3(QKVN/128, M_TOK/64), 256, 0, stream>>>(nx, wqkvb, bqkv, qkv, nullptr, nullptr, M_TOK, QKVN, D, 0);
  attn_kernel<<<M_TOK, 256, 0, stream>>>(qkv, mask, pk, cx);
  gemm_lds<64,64,2,2><<<dim3(D/64, M_TOK/64), 256, 0, stream>>>(cx, wob, bo, nullptr, x1, x, M_TOK, D, D, 0);
  ln_kernel<<<M_TOK/4, 256, 0, stream>>>(x1, ln2g, ln2b, n2);
  gemm_lds<128,128,2,2><<<dim3(DFF/128, M_TOK/128), 256, 0, stream>>>(n2, w1b, b1, hb, nullptr, nullptr, M_TOK, DFF, D, 1);
  gemm_lds<64,64,2,2><<<dim3(D/64, M_TOK/64), 256, 0, stream>>>(hb, w2b, b2, nullptr, out, x1, M_TOK, D, DFF, 0);
}